// Round 12
// baseline (110.530 us; speedup 1.0000x reference)
//
#include <hip/hip_runtime.h>

#define S 48
#define D 4
#define PADC 2
#define P 52
#define SITES (S * S * S)        // 110592
#define PADVOL (P * P * P)       // 140608
#define N_IN 2048
#define H1 1024
#define H2 128
#define OUTN 10
#define RP 64                    // rows per gemv1 block
#define NCH (SITES / RP)         // 1728
#define RG 16                    // row-groups in reduce stage A
#define CHPG (NCH / RG)          // 108 chunks per group
#define G2B 32                   // gemv2 blocks (32 y1-rows each)
#define WARM4 884736             // float4s warmed per step (14.15 MB)

__global__ __launch_bounds__(256) void zero_k(float4* __restrict__ p, int n4,
                                              int* __restrict__ cnt) {
    int i = blockIdx.x * 256 + threadIdx.x;
    if (i < n4) p[i] = make_float4(0.f, 0.f, 0.f, 0.f);
    if (i == 0) *cnt = 0;
}

__global__ void scatter_k(const float* __restrict__ vin,
                          const int* __restrict__ idx,
                          float* __restrict__ nm) {
    int t = blockIdx.x * blockDim.x + threadIdx.x;
    if (t < N_IN) {
        int x = idx[t * 3 + 0] + PADC;
        int y = idx[t * 3 + 1] + PADC;
        int z = idx[t * 3 + 2] + PADC;
        atomicAdd(&nm[(x * P + y) * P + z], vin[t]);
    }
}

// 4 lanes per site (R5/R7 proven). Extra: warms a 14 MB slice of W1 into L3
// (HBM is otherwise idle during the recurrence; values discarded).
__global__ __launch_bounds__(256) void step_k(const float* __restrict__ src,
                                              const float* __restrict__ syn,
                                              float* __restrict__ dst,
                                              const float4* __restrict__ w1warm,
                                              int step) {
    int tid = threadIdx.x;
    int q = tid & 3;                          // b-index
    int sl = tid >> 2;                        // 0..63
    int s = blockIdx.x * 64 + sl;
    int z = s % S;
    int t2 = s / S;
    int y = t2 % S;
    int x = t2 / S;
    const float4* sv = (const float4*)(syn + (size_t)s * 64);

    // issue warm loads early; independent of site work
    size_t gt = (size_t)blockIdx.x * 256 + tid;
    float4 wm0 = w1warm[(size_t)step * WARM4 + gt * 2];
    float4 wm1 = w1warm[(size_t)step * WARM4 + gt * 2 + 1];

    float acc = 0.0f;
#pragma unroll
    for (int a = 0; a < D; a++) {
        const float* row = src + ((x + a) * P + (y + q)) * P + z;
        float4 w = sv[a * 4 + q];
        acc += w.x * row[0] + w.y * row[1] + w.z * row[2] + w.w * row[3];
    }
    acc += __shfl_xor(acc, 1);
    acc += __shfl_xor(acc, 2);
    if (q == 0) {
        dst[((x + PADC) * P + (y + PADC)) * P + (z + PADC)] = fmaxf(acc, 0.0f) * 0.9f;
    }
    // keep warm loads alive (anti-DCE), all 8 components so b128 isn't narrowed
    asm volatile("" :: "v"(wm0.x), "v"(wm0.y), "v"(wm0.z), "v"(wm0.w),
                       "v"(wm1.x), "v"(wm1.y), "v"(wm1.z), "v"(wm1.w));
}

// Layer-1 GEMV (R7 proven): wave-uniform SGPR bitmask row skip, 4-way
// unrolled bit-loop, readlane broadcast.
__global__ __launch_bounds__(256) void gemv1_k(const float* __restrict__ nmfin,
                                               const float* __restrict__ W1,
                                               float* __restrict__ partial) {
    int t = threadIdx.x;
    int lane = t & 63;
    int i0 = blockIdx.x * RP;

    int i = i0 + lane;
    int z = i % S;
    int q = i / S;
    int y = q % S;
    int x = q / S;
    float v = nmfin[((x + PADC) * P + (y + PADC)) * P + (z + PADC)];
    unsigned long long mask = __ballot(v != 0.0f);

    const float4* W4 = (const float4*)W1;
    size_t base = (size_t)i0 * (H1 / 4) + t;
    float4 a0 = {0.f, 0.f, 0.f, 0.f};
    float4 a1 = {0.f, 0.f, 0.f, 0.f};
    float4 a2 = {0.f, 0.f, 0.f, 0.f};
    float4 a3 = {0.f, 0.f, 0.f, 0.f};
    int nnz = __popcll(mask);
    for (int k = 0; k + 4 <= nnz; k += 4) {
        int r0 = (int)__builtin_ctzll(mask); mask &= mask - 1;
        int r1 = (int)__builtin_ctzll(mask); mask &= mask - 1;
        int r2 = (int)__builtin_ctzll(mask); mask &= mask - 1;
        int r3 = (int)__builtin_ctzll(mask); mask &= mask - 1;
        float x0 = __int_as_float(__builtin_amdgcn_readlane(__float_as_int(v), r0));
        float x1 = __int_as_float(__builtin_amdgcn_readlane(__float_as_int(v), r1));
        float x2 = __int_as_float(__builtin_amdgcn_readlane(__float_as_int(v), r2));
        float x3 = __int_as_float(__builtin_amdgcn_readlane(__float_as_int(v), r3));
        float4 w0 = W4[base + (size_t)r0 * (H1 / 4)];
        float4 w1 = W4[base + (size_t)r1 * (H1 / 4)];
        float4 w2 = W4[base + (size_t)r2 * (H1 / 4)];
        float4 w3 = W4[base + (size_t)r3 * (H1 / 4)];
        a0.x += x0 * w0.x; a0.y += x0 * w0.y; a0.z += x0 * w0.z; a0.w += x0 * w0.w;
        a1.x += x1 * w1.x; a1.y += x1 * w1.y; a1.z += x1 * w1.z; a1.w += x1 * w1.w;
        a2.x += x2 * w2.x; a2.y += x2 * w2.y; a2.z += x2 * w2.z; a2.w += x2 * w2.w;
        a3.x += x3 * w3.x; a3.y += x3 * w3.y; a3.z += x3 * w3.z; a3.w += x3 * w3.w;
    }
    while (mask) {
        int r0 = (int)__builtin_ctzll(mask); mask &= mask - 1;
        float x0 = __int_as_float(__builtin_amdgcn_readlane(__float_as_int(v), r0));
        float4 w0 = W4[base + (size_t)r0 * (H1 / 4)];
        a0.x += x0 * w0.x; a0.y += x0 * w0.y; a0.z += x0 * w0.z; a0.w += x0 * w0.w;
    }
    float4 acc = {a0.x + a1.x + a2.x + a3.x,
                  a0.y + a1.y + a2.y + a3.y,
                  a0.z + a1.z + a2.z + a3.z,
                  a0.w + a1.w + a2.w + a3.w};
    ((float4*)(partial + (size_t)blockIdx.x * H1))[t] = acc;
}

// reduce stage A (R7 proven): 64 blocks x 256 threads.
__global__ __launch_bounds__(256) void reduceA_k(const float* __restrict__ partial,
                                                 float* __restrict__ redB) {
    int g = blockIdx.x >> 2;
    int c = (blockIdx.x & 3) * 256 + threadIdx.x;
    float s = 0.0f;
    int r0 = g * CHPG;
#pragma unroll 4
    for (int r = r0; r < r0 + CHPG; r++) s += partial[(size_t)r * H1 + c];
    redB[g * H1 + c] = s;
}

// gemv2 + fused final (R11-proven arrival-counter mechanism).
__global__ __launch_bounds__(128) void gemv2f_k(const float* __restrict__ redB,
                                                const float* __restrict__ b1,
                                                const float* __restrict__ W2,
                                                const float* __restrict__ b2,
                                                const float* __restrict__ W3,
                                                const float* __restrict__ b3,
                                                float* __restrict__ partial2,
                                                int* __restrict__ cnt,
                                                float* __restrict__ out) {
    __shared__ float ys[H1 / G2B];            // 32
    __shared__ int amlast;
    int b = blockIdx.x;
    int t = threadIdx.x;
    int r0 = b * (H1 / G2B);
    if (t < H1 / G2B) {
        int j = r0 + t;
        float s = b1[j];
#pragma unroll
        for (int g = 0; g < RG; g++) s += redB[g * H1 + j];
        ys[t] = fmaxf(s, 0.0f);
    }
    __syncthreads();
    float acc = 0.0f;
#pragma unroll
    for (int i = 0; i < H1 / G2B; i++)
        acc += ys[i] * W2[(size_t)(r0 + i) * H2 + t];
    partial2[b * H2 + t] = acc;

    __threadfence();
    __syncthreads();
    if (t == 0) {
        int prev = atomicAdd(cnt, 1);
        amlast = (prev == G2B - 1) ? 1 : 0;
    }
    __syncthreads();
    if (amlast) {
        __threadfence();
        __shared__ float y2[H2];
        float s2 = b2[t];
#pragma unroll
        for (int k = 0; k < G2B; k++) s2 += partial2[k * H2 + t];
        y2[t] = fmaxf(s2, 0.0f);
        __syncthreads();
        if (t < OUTN) {
            float o = b3[t];
#pragma unroll 8
            for (int k = 0; k < H2; k++) o += y2[k] * W3[k * OUTN + t];
            out[t] = o;
        }
    }
}

extern "C" void kernel_launch(void* const* d_in, const int* in_sizes, int n_in,
                              void* d_out, int out_size, void* d_ws, size_t ws_size,
                              hipStream_t stream) {
    const float* vinput  = (const float*)d_in[1];
    const float* synapse = (const float*)d_in[2];
    const float* W1      = (const float*)d_in[3];
    const float* b1      = (const float*)d_in[4];
    const float* W2      = (const float*)d_in[5];
    const float* b2      = (const float*)d_in[6];
    const float* W3      = (const float*)d_in[7];
    const float* b3      = (const float*)d_in[8];
    const int* node_idx  = (const int*)d_in[9];

    float* ws = (float*)d_ws;
    float* nm0 = ws;                            // PADVOL
    float* nm1 = nm0 + PADVOL;                  // PADVOL
    float* partial1 = nm1 + PADVOL;             // NCH * 1024
    float* redB = partial1 + (size_t)NCH * H1;  // 16 * 1024
    float* partial2 = redB + RG * H1;           // G2B * 128
    int* cnt = (int*)(partial2 + G2B * H2);     // 1 int
    float* out = (float*)d_out;

    // zero both nm buffers + arrival counter
    const int n4 = 2 * PADVOL / 4;              // 70304 float4s
    zero_k<<<(n4 + 255) / 256, 256, 0, stream>>>((float4*)nm0, n4, cnt);

    scatter_k<<<N_IN / 256, 256, 0, stream>>>(vinput, node_idx, nm0);

    const float* src = nm0;
    float* dst = nm1;
    for (int r = 0; r < 5; r++) {
        step_k<<<SITES / 64, 256, 0, stream>>>(src, synapse, dst,
                                               (const float4*)W1, r);
        float* tmp = (float*)src;
        src = dst;
        dst = tmp;
    }
    // final interior lives in nm1 (5 steps)

    gemv1_k<<<NCH, 256, 0, stream>>>(nm1, W1, partial1);
    reduceA_k<<<RG * 4, 256, 0, stream>>>(partial1, redB);
    gemv2f_k<<<G2B, 128, 0, stream>>>(redB, b1, W2, b2, W3, b3,
                                      partial2, cnt, out);
}

// Round 13
// 92.827 us; speedup vs baseline: 1.1907x; 1.1907x over previous
//
#include <hip/hip_runtime.h>

#define S 48
#define D 4
#define PADC 2
#define P 52
#define SITES (S * S * S)        // 110592
#define PADVOL (P * P * P)       // 140608
#define N_IN 2048
#define H1 1024
#define H2 128
#define OUTN 10
#define RP 64                    // rows per gemv1 block
#define NCH (SITES / RP)         // 1728
#define RG 16                    // row-groups in reduce stage A
#define CHPG (NCH / RG)          // 108 chunks per group
#define G2B 32                   // gemv2 blocks (32 y1-rows each)

__global__ __launch_bounds__(256) void zero_k(float4* __restrict__ p, int n4,
                                              int* __restrict__ cnt) {
    int i = blockIdx.x * 256 + threadIdx.x;
    if (i < n4) p[i] = make_float4(0.f, 0.f, 0.f, 0.f);
    if (i == 0) *cnt = 0;
}

__global__ void scatter_k(const float* __restrict__ vin,
                          const int* __restrict__ idx,
                          float* __restrict__ nm) {
    int t = blockIdx.x * blockDim.x + threadIdx.x;
    if (t < N_IN) {
        int x = idx[t * 3 + 0] + PADC;
        int y = idx[t * 3 + 1] + PADC;
        int z = idx[t * 3 + 2] + PADC;
        atomicAdd(&nm[(x * P + y) * P + z], vin[t]);
    }
}

// 4 lanes per site (R5/R7 proven): lane-group of 4 splits the b-dim,
// combined with two shfl_xor. 1728 blocks -> 6.75 waves/SIMD.
__global__ __launch_bounds__(256) void step_k(const float* __restrict__ src,
                                              const float* __restrict__ syn,
                                              float* __restrict__ dst) {
    int tid = threadIdx.x;
    int q = tid & 3;                          // b-index
    int sl = tid >> 2;                        // 0..63
    int s = blockIdx.x * 64 + sl;
    int z = s % S;
    int t2 = s / S;
    int y = t2 % S;
    int x = t2 / S;
    const float4* sv = (const float4*)(syn + (size_t)s * 64);
    float acc = 0.0f;
#pragma unroll
    for (int a = 0; a < D; a++) {
        const float* row = src + ((x + a) * P + (y + q)) * P + z;
        float4 w = sv[a * 4 + q];
        acc += w.x * row[0] + w.y * row[1] + w.z * row[2] + w.w * row[3];
    }
    acc += __shfl_xor(acc, 1);
    acc += __shfl_xor(acc, 2);
    if (q == 0) {
        dst[((x + PADC) * P + (y + PADC)) * P + (z + PADC)] = fmaxf(acc, 0.0f) * 0.9f;
    }
}

// Layer-1 GEMV (R7 proven): wave-uniform SGPR bitmask row skip, 4-way
// unrolled bit-loop, readlane broadcast (no LDS, no syncthreads).
__global__ __launch_bounds__(256) void gemv1_k(const float* __restrict__ nmfin,
                                               const float* __restrict__ W1,
                                               float* __restrict__ partial) {
    int t = threadIdx.x;
    int lane = t & 63;
    int i0 = blockIdx.x * RP;

    int i = i0 + lane;
    int z = i % S;
    int q = i / S;
    int y = q % S;
    int x = q / S;
    float v = nmfin[((x + PADC) * P + (y + PADC)) * P + (z + PADC)];
    unsigned long long mask = __ballot(v != 0.0f);

    const float4* W4 = (const float4*)W1;
    size_t base = (size_t)i0 * (H1 / 4) + t;
    float4 a0 = {0.f, 0.f, 0.f, 0.f};
    float4 a1 = {0.f, 0.f, 0.f, 0.f};
    float4 a2 = {0.f, 0.f, 0.f, 0.f};
    float4 a3 = {0.f, 0.f, 0.f, 0.f};
    int nnz = __popcll(mask);
    for (int k = 0; k + 4 <= nnz; k += 4) {
        int r0 = (int)__builtin_ctzll(mask); mask &= mask - 1;
        int r1 = (int)__builtin_ctzll(mask); mask &= mask - 1;
        int r2 = (int)__builtin_ctzll(mask); mask &= mask - 1;
        int r3 = (int)__builtin_ctzll(mask); mask &= mask - 1;
        float x0 = __int_as_float(__builtin_amdgcn_readlane(__float_as_int(v), r0));
        float x1 = __int_as_float(__builtin_amdgcn_readlane(__float_as_int(v), r1));
        float x2 = __int_as_float(__builtin_amdgcn_readlane(__float_as_int(v), r2));
        float x3 = __int_as_float(__builtin_amdgcn_readlane(__float_as_int(v), r3));
        float4 w0 = W4[base + (size_t)r0 * (H1 / 4)];
        float4 w1 = W4[base + (size_t)r1 * (H1 / 4)];
        float4 w2 = W4[base + (size_t)r2 * (H1 / 4)];
        float4 w3 = W4[base + (size_t)r3 * (H1 / 4)];
        a0.x += x0 * w0.x; a0.y += x0 * w0.y; a0.z += x0 * w0.z; a0.w += x0 * w0.w;
        a1.x += x1 * w1.x; a1.y += x1 * w1.y; a1.z += x1 * w1.z; a1.w += x1 * w1.w;
        a2.x += x2 * w2.x; a2.y += x2 * w2.y; a2.z += x2 * w2.z; a2.w += x2 * w2.w;
        a3.x += x3 * w3.x; a3.y += x3 * w3.y; a3.z += x3 * w3.z; a3.w += x3 * w3.w;
    }
    while (mask) {
        int r0 = (int)__builtin_ctzll(mask); mask &= mask - 1;
        float x0 = __int_as_float(__builtin_amdgcn_readlane(__float_as_int(v), r0));
        float4 w0 = W4[base + (size_t)r0 * (H1 / 4)];
        a0.x += x0 * w0.x; a0.y += x0 * w0.y; a0.z += x0 * w0.z; a0.w += x0 * w0.w;
    }
    float4 acc = {a0.x + a1.x + a2.x + a3.x,
                  a0.y + a1.y + a2.y + a3.y,
                  a0.z + a1.z + a2.z + a3.z,
                  a0.w + a1.w + a2.w + a3.w};
    ((float4*)(partial + (size_t)blockIdx.x * H1))[t] = acc;
}

// reduce stage A (R7 proven): 64 blocks x 256 threads.
__global__ __launch_bounds__(256) void reduceA_k(const float* __restrict__ partial,
                                                 float* __restrict__ redB) {
    int g = blockIdx.x >> 2;
    int c = (blockIdx.x & 3) * 256 + threadIdx.x;
    float s = 0.0f;
    int r0 = g * CHPG;
#pragma unroll 4
    for (int r = r0; r < r0 + CHPG; r++) s += partial[(size_t)r * H1 + c];
    redB[g * H1 + c] = s;
}

// gemv2 + fused final via arrival counter (mechanism proven R10-R12):
// block b computes y1 rows [b*32,b*32+32) from redB, its W2 partial; the
// last block to arrive computes layer-2 finish + layer-3 (fixed order).
__global__ __launch_bounds__(128) void gemv2f_k(const float* __restrict__ redB,
                                                const float* __restrict__ b1,
                                                const float* __restrict__ W2,
                                                const float* __restrict__ b2,
                                                const float* __restrict__ W3,
                                                const float* __restrict__ b3,
                                                float* __restrict__ partial2,
                                                int* __restrict__ cnt,
                                                float* __restrict__ out) {
    __shared__ float ys[H1 / G2B];            // 32
    __shared__ int amlast;
    int b = blockIdx.x;
    int t = threadIdx.x;
    int r0 = b * (H1 / G2B);
    if (t < H1 / G2B) {
        int j = r0 + t;
        float s = b1[j];
#pragma unroll
        for (int g = 0; g < RG; g++) s += redB[g * H1 + j];
        ys[t] = fmaxf(s, 0.0f);
    }
    __syncthreads();
    float acc = 0.0f;
#pragma unroll
    for (int i = 0; i < H1 / G2B; i++)
        acc += ys[i] * W2[(size_t)(r0 + i) * H2 + t];
    partial2[b * H2 + t] = acc;

    __threadfence();
    __syncthreads();
    if (t == 0) {
        int prev = atomicAdd(cnt, 1);
        amlast = (prev == G2B - 1) ? 1 : 0;
    }
    __syncthreads();
    if (amlast) {
        __threadfence();
        __shared__ float y2[H2];
        float s2 = b2[t];
#pragma unroll
        for (int k = 0; k < G2B; k++) s2 += partial2[k * H2 + t];
        y2[t] = fmaxf(s2, 0.0f);
        __syncthreads();
        if (t < OUTN) {
            float o = b3[t];
#pragma unroll 8
            for (int k = 0; k < H2; k++) o += y2[k] * W3[k * OUTN + t];
            out[t] = o;
        }
    }
}

extern "C" void kernel_launch(void* const* d_in, const int* in_sizes, int n_in,
                              void* d_out, int out_size, void* d_ws, size_t ws_size,
                              hipStream_t stream) {
    const float* vinput  = (const float*)d_in[1];
    const float* synapse = (const float*)d_in[2];
    const float* W1      = (const float*)d_in[3];
    const float* b1      = (const float*)d_in[4];
    const float* W2      = (const float*)d_in[5];
    const float* b2      = (const float*)d_in[6];
    const float* W3      = (const float*)d_in[7];
    const float* b3      = (const float*)d_in[8];
    const int* node_idx  = (const int*)d_in[9];

    float* ws = (float*)d_ws;
    float* nm0 = ws;                            // PADVOL
    float* nm1 = nm0 + PADVOL;                  // PADVOL
    float* partial1 = nm1 + PADVOL;             // NCH * 1024
    float* redB = partial1 + (size_t)NCH * H1;  // 16 * 1024
    float* partial2 = redB + RG * H1;           // G2B * 128
    int* cnt = (int*)(partial2 + G2B * H2);     // 1 int
    float* out = (float*)d_out;

    // zero both nm buffers + arrival counter
    const int n4 = 2 * PADVOL / 4;              // 70304 float4s
    zero_k<<<(n4 + 255) / 256, 256, 0, stream>>>((float4*)nm0, n4, cnt);

    scatter_k<<<N_IN / 256, 256, 0, stream>>>(vinput, node_idx, nm0);

    const float* src = nm0;
    float* dst = nm1;
    for (int r = 0; r < 5; r++) {
        step_k<<<SITES / 64, 256, 0, stream>>>(src, synapse, dst);
        float* tmp = (float*)src;
        src = dst;
        dst = tmp;
    }
    // final interior lives in nm1 (5 steps)

    gemv1_k<<<NCH, 256, 0, stream>>>(nm1, W1, partial1);
    reduceA_k<<<RG * 4, 256, 0, stream>>>(partial1, redB);
    gemv2f_k<<<G2B, 128, 0, stream>>>(redB, b1, W2, b2, W3, b3,
                                      partial2, cnt, out);
}

// Round 14
// 91.287 us; speedup vs baseline: 1.2108x; 1.0169x over previous
//
#include <hip/hip_runtime.h>

#define S 48
#define D 4
#define PADC 2
#define P 52
#define SITES (S * S * S)        // 110592
#define PADVOL (P * P * P)       // 140608
#define N_IN 2048
#define H1 1024
#define H2 128
#define OUTN 10
#define RP 64                    // rows per gemv1 block
#define NCH (SITES / RP)         // 1728
#define RG 16                    // row-groups in reduce stage A
#define CHPG (NCH / RG)          // 108 chunks per group
#define G2B 32                   // gemv2 blocks (32 y1-rows each)

__global__ __launch_bounds__(256) void zero_k(float4* __restrict__ p, int n4,
                                              int* __restrict__ cnt) {
    int i = blockIdx.x * 256 + threadIdx.x;
    if (i < n4) p[i] = make_float4(0.f, 0.f, 0.f, 0.f);
    if (i == 0) *cnt = 0;
}

__global__ void scatter_k(const float* __restrict__ vin,
                          const int* __restrict__ idx,
                          float* __restrict__ nm) {
    int t = blockIdx.x * blockDim.x + threadIdx.x;
    if (t < N_IN) {
        int x = idx[t * 3 + 0] + PADC;
        int y = idx[t * 3 + 1] + PADC;
        int z = idx[t * 3 + 2] + PADC;
        atomicAdd(&nm[(x * P + y) * P + z], vin[t]);
    }
}

// 4 lanes per site (R5/R7 proven): lane-group of 4 splits the b-dim,
// combined with two shfl_xor. 1728 blocks -> 6.75 waves/SIMD.
__global__ __launch_bounds__(256) void step_k(const float* __restrict__ src,
                                              const float* __restrict__ syn,
                                              float* __restrict__ dst) {
    int tid = threadIdx.x;
    int q = tid & 3;                          // b-index
    int sl = tid >> 2;                        // 0..63
    int s = blockIdx.x * 64 + sl;
    int z = s % S;
    int t2 = s / S;
    int y = t2 % S;
    int x = t2 / S;
    const float4* sv = (const float4*)(syn + (size_t)s * 64);
    float acc = 0.0f;
#pragma unroll
    for (int a = 0; a < D; a++) {
        const float* row = src + ((x + a) * P + (y + q)) * P + z;
        float4 w = sv[a * 4 + q];
        acc += w.x * row[0] + w.y * row[1] + w.z * row[2] + w.w * row[3];
    }
    acc += __shfl_xor(acc, 1);
    acc += __shfl_xor(acc, 2);
    if (q == 0) {
        dst[((x + PADC) * P + (y + PADC)) * P + (z + PADC)] = fmaxf(acc, 0.0f) * 0.9f;
    }
}

// Layer-1 GEMV with COOPERATIVE fused step-5 (no redundancy, unlike R11):
// prologue = step_k's exact 4-lane/site pattern for this block's 64 sites
// (256 threads, zero duplicated work), values published via LDS; then the
// proven wave-uniform SGPR-bitmask 4-way-unrolled W1 stream.
__global__ __launch_bounds__(256) void gemv1f_k(const float* __restrict__ src,
                                                const float* __restrict__ syn,
                                                const float* __restrict__ W1,
                                                float* __restrict__ partial) {
    __shared__ float xs[RP];
    int tid = threadIdx.x;
    int i0 = blockIdx.x * RP;

    // --- cooperative step 5 for sites i0..i0+63 ---
    {
        int q = tid & 3;                      // b-index
        int sl = tid >> 2;                    // 0..63
        int s = i0 + sl;
        int z = s % S;
        int t2 = s / S;
        int y = t2 % S;
        int x = t2 / S;
        const float4* sv = (const float4*)(syn + (size_t)s * 64);
        float acc = 0.0f;
#pragma unroll
        for (int a = 0; a < D; a++) {
            const float* row = src + ((x + a) * P + (y + q)) * P + z;
            float4 w = sv[a * 4 + q];
            acc += w.x * row[0] + w.y * row[1] + w.z * row[2] + w.w * row[3];
        }
        acc += __shfl_xor(acc, 1);
        acc += __shfl_xor(acc, 2);
        if (q == 0) xs[sl] = fmaxf(acc, 0.0f) * 0.9f;
    }
    __syncthreads();

    // --- W1 stream (R7 proven) ---
    int lane = tid & 63;
    float v = xs[lane];                       // same 64 values in every wave
    unsigned long long mask = __ballot(v != 0.0f);

    const float4* W4 = (const float4*)W1;
    size_t base = (size_t)i0 * (H1 / 4) + tid;
    float4 a0 = {0.f, 0.f, 0.f, 0.f};
    float4 a1 = {0.f, 0.f, 0.f, 0.f};
    float4 a2 = {0.f, 0.f, 0.f, 0.f};
    float4 a3 = {0.f, 0.f, 0.f, 0.f};
    int nnz = __popcll(mask);
    for (int k = 0; k + 4 <= nnz; k += 4) {
        int r0 = (int)__builtin_ctzll(mask); mask &= mask - 1;
        int r1 = (int)__builtin_ctzll(mask); mask &= mask - 1;
        int r2 = (int)__builtin_ctzll(mask); mask &= mask - 1;
        int r3 = (int)__builtin_ctzll(mask); mask &= mask - 1;
        float x0 = __int_as_float(__builtin_amdgcn_readlane(__float_as_int(v), r0));
        float x1 = __int_as_float(__builtin_amdgcn_readlane(__float_as_int(v), r1));
        float x2 = __int_as_float(__builtin_amdgcn_readlane(__float_as_int(v), r2));
        float x3 = __int_as_float(__builtin_amdgcn_readlane(__float_as_int(v), r3));
        float4 w0 = W4[base + (size_t)r0 * (H1 / 4)];
        float4 w1 = W4[base + (size_t)r1 * (H1 / 4)];
        float4 w2 = W4[base + (size_t)r2 * (H1 / 4)];
        float4 w3 = W4[base + (size_t)r3 * (H1 / 4)];
        a0.x += x0 * w0.x; a0.y += x0 * w0.y; a0.z += x0 * w0.z; a0.w += x0 * w0.w;
        a1.x += x1 * w1.x; a1.y += x1 * w1.y; a1.z += x1 * w1.z; a1.w += x1 * w1.w;
        a2.x += x2 * w2.x; a2.y += x2 * w2.y; a2.z += x2 * w2.z; a2.w += x2 * w2.w;
        a3.x += x3 * w3.x; a3.y += x3 * w3.y; a3.z += x3 * w3.z; a3.w += x3 * w3.w;
    }
    while (mask) {
        int r0 = (int)__builtin_ctzll(mask); mask &= mask - 1;
        float x0 = __int_as_float(__builtin_amdgcn_readlane(__float_as_int(v), r0));
        float4 w0 = W4[base + (size_t)r0 * (H1 / 4)];
        a0.x += x0 * w0.x; a0.y += x0 * w0.y; a0.z += x0 * w0.z; a0.w += x0 * w0.w;
    }
    float4 acc = {a0.x + a1.x + a2.x + a3.x,
                  a0.y + a1.y + a2.y + a3.y,
                  a0.z + a1.z + a2.z + a3.z,
                  a0.w + a1.w + a2.w + a3.w};
    ((float4*)(partial + (size_t)blockIdx.x * H1))[tid] = acc;
}

// reduce stage A (R7 proven): 64 blocks x 256 threads.
__global__ __launch_bounds__(256) void reduceA_k(const float* __restrict__ partial,
                                                 float* __restrict__ redB) {
    int g = blockIdx.x >> 2;
    int c = (blockIdx.x & 3) * 256 + threadIdx.x;
    float s = 0.0f;
    int r0 = g * CHPG;
#pragma unroll 4
    for (int r = r0; r < r0 + CHPG; r++) s += partial[(size_t)r * H1 + c];
    redB[g * H1 + c] = s;
}

// gemv2 + fused final via arrival counter (mechanism proven R10-R13).
__global__ __launch_bounds__(128) void gemv2f_k(const float* __restrict__ redB,
                                                const float* __restrict__ b1,
                                                const float* __restrict__ W2,
                                                const float* __restrict__ b2,
                                                const float* __restrict__ W3,
                                                const float* __restrict__ b3,
                                                float* __restrict__ partial2,
                                                int* __restrict__ cnt,
                                                float* __restrict__ out) {
    __shared__ float ys[H1 / G2B];            // 32
    __shared__ int amlast;
    int b = blockIdx.x;
    int t = threadIdx.x;
    int r0 = b * (H1 / G2B);
    if (t < H1 / G2B) {
        int j = r0 + t;
        float s = b1[j];
#pragma unroll
        for (int g = 0; g < RG; g++) s += redB[g * H1 + j];
        ys[t] = fmaxf(s, 0.0f);
    }
    __syncthreads();
    float acc = 0.0f;
#pragma unroll
    for (int i = 0; i < H1 / G2B; i++)
        acc += ys[i] * W2[(size_t)(r0 + i) * H2 + t];
    partial2[b * H2 + t] = acc;

    __threadfence();
    __syncthreads();
    if (t == 0) {
        int prev = atomicAdd(cnt, 1);
        amlast = (prev == G2B - 1) ? 1 : 0;
    }
    __syncthreads();
    if (amlast) {
        __threadfence();
        __shared__ float y2[H2];
        float s2 = b2[t];
#pragma unroll
        for (int k = 0; k < G2B; k++) s2 += partial2[k * H2 + t];
        y2[t] = fmaxf(s2, 0.0f);
        __syncthreads();
        if (t < OUTN) {
            float o = b3[t];
#pragma unroll 8
            for (int k = 0; k < H2; k++) o += y2[k] * W3[k * OUTN + t];
            out[t] = o;
        }
    }
}

extern "C" void kernel_launch(void* const* d_in, const int* in_sizes, int n_in,
                              void* d_out, int out_size, void* d_ws, size_t ws_size,
                              hipStream_t stream) {
    const float* vinput  = (const float*)d_in[1];
    const float* synapse = (const float*)d_in[2];
    const float* W1      = (const float*)d_in[3];
    const float* b1      = (const float*)d_in[4];
    const float* W2      = (const float*)d_in[5];
    const float* b2      = (const float*)d_in[6];
    const float* W3      = (const float*)d_in[7];
    const float* b3      = (const float*)d_in[8];
    const int* node_idx  = (const int*)d_in[9];

    float* ws = (float*)d_ws;
    float* nm0 = ws;                            // PADVOL
    float* nm1 = nm0 + PADVOL;                  // PADVOL
    float* partial1 = nm1 + PADVOL;             // NCH * 1024
    float* redB = partial1 + (size_t)NCH * H1;  // 16 * 1024
    float* partial2 = redB + RG * H1;           // G2B * 128
    int* cnt = (int*)(partial2 + G2B * H2);     // 1 int
    float* out = (float*)d_out;

    // zero both nm buffers + arrival counter
    const int n4 = 2 * PADVOL / 4;              // 70304 float4s
    zero_k<<<(n4 + 255) / 256, 256, 0, stream>>>((float4*)nm0, n4, cnt);

    scatter_k<<<N_IN / 256, 256, 0, stream>>>(vinput, node_idx, nm0);

    // steps 1..4 as dispatches; step 5 fused (cooperatively) into gemv1f
    const float* src = nm0;
    float* dst = nm1;
    for (int r = 0; r < 4; r++) {
        step_k<<<SITES / 64, 256, 0, stream>>>(src, synapse, dst);
        float* tmp = (float*)src;
        src = dst;
        dst = tmp;
    }
    // after 4 steps the state is back in nm0

    gemv1f_k<<<NCH, 256, 0, stream>>>(src, synapse, W1, partial1);
    reduceA_k<<<RG * 4, 256, 0, stream>>>(partial1, redB);
    gemv2f_k<<<G2B, 128, 0, stream>>>(redB, b1, W2, b2, W3, b3,
                                      partial2, cnt, out);
}